// Round 1
// 126.426 us; speedup vs baseline: 1.1405x; 1.1405x over previous
//
#include <hip/hip_runtime.h>

// VectorQuantizer: x [32,64,64,64] f32, emb [512,64] f32 -> out [32,64,64,64] f32
// R11: MPB=64 restructure of the R10 register-resident screen.
//  - 2048 blocks x 512 thr; each wave: 64 codes x 64 pixels (mt=4), s[4][4][4]
//  - ebf B-frags + e_sq prefetched to regs BEFORE the staging barrier
//  - margin folded into the atomicMin value (bit-identical threshold:
//    min_w fl(v+m) == fl(min_w v + m) by monotonicity)
//  - candidate rescore inlined at detection via 64-bit mask + ctz loop
//    (no queue, no QCAP overflow hazard); 3 barriers total
//  - vq_prep parallelized to 8 blocks x 64 thr (register float4 staging,
//    identical summation order -> identical bits)
// Exact-score semantics unchanged from R8/R9 (absmax==0): sequential-c fmaf
// dot, pairwise-8 sums, _rn combine, lexicographic (se,k) u64 atomicMin.

#define KNUM 512
#define CDIM 64
#define MPB  64

typedef __attribute__((ext_vector_type(8))) short bf16x8;
typedef __attribute__((ext_vector_type(4))) float f32x4;

__device__ __forceinline__ unsigned f2bf(float f) {   // RNE f32->bf16
    unsigned u = __float_as_uint(f);
    return (u + 0x7FFFu + ((u >> 16) & 1u)) >> 16;
}
__device__ __forceinline__ unsigned ordf(float f) {   // total-order encode
    unsigned u = __float_as_uint(f);
    return u ^ ((unsigned)(((int)u) >> 31) | 0x80000000u);
}
__device__ __forceinline__ float ordinv(unsigned u) {
    unsigned fb = (u & 0x80000000u) ? (u ^ 0x80000000u) : ~u;
    return __uint_as_float(fb);
}

__device__ __forceinline__ float xsq_pairwise8(const float* xr)   // np order
{
    float r[8];
    {
        const float4 a = *(const float4*)&xr[0];
        const float4 c = *(const float4*)&xr[4];
        r[0] = __fmul_rn(a.x, a.x); r[1] = __fmul_rn(a.y, a.y);
        r[2] = __fmul_rn(a.z, a.z); r[3] = __fmul_rn(a.w, a.w);
        r[4] = __fmul_rn(c.x, c.x); r[5] = __fmul_rn(c.y, c.y);
        r[6] = __fmul_rn(c.z, c.z); r[7] = __fmul_rn(c.w, c.w);
    }
    #pragma unroll
    for (int i = 1; i < 8; ++i) {
        const float4 a = *(const float4*)&xr[8 * i];
        const float4 c = *(const float4*)&xr[8 * i + 4];
        r[0] = __fadd_rn(r[0], __fmul_rn(a.x, a.x));
        r[1] = __fadd_rn(r[1], __fmul_rn(a.y, a.y));
        r[2] = __fadd_rn(r[2], __fmul_rn(a.z, a.z));
        r[3] = __fadd_rn(r[3], __fmul_rn(a.w, a.w));
        r[4] = __fadd_rn(r[4], __fmul_rn(c.x, c.x));
        r[5] = __fadd_rn(r[5], __fmul_rn(c.y, c.y));
        r[6] = __fadd_rn(r[6], __fmul_rn(c.z, c.z));
        r[7] = __fadd_rn(r[7], __fmul_rn(c.w, c.w));
    }
    return __fadd_rn(
        __fadd_rn(__fadd_rn(r[0], r[1]), __fadd_rn(r[2], r[3])),
        __fadd_rn(__fadd_rn(r[4], r[5]), __fadd_rn(r[6], r[7])));
}

__global__ __launch_bounds__(64) void vq_prep(const float* __restrict__ emb,
                                              float* __restrict__ e_sq,
                                              unsigned* __restrict__ ebf)
{
    const int k = blockIdx.x * 64 + threadIdx.x;
    const float* e = emb + k * CDIM;
    float4 f[16];
    #pragma unroll
    for (int i = 0; i < 16; ++i) f[i] = ((const float4*)e)[i];

    float r[8];
    r[0] = __fmul_rn(f[0].x, f[0].x); r[1] = __fmul_rn(f[0].y, f[0].y);
    r[2] = __fmul_rn(f[0].z, f[0].z); r[3] = __fmul_rn(f[0].w, f[0].w);
    r[4] = __fmul_rn(f[1].x, f[1].x); r[5] = __fmul_rn(f[1].y, f[1].y);
    r[6] = __fmul_rn(f[1].z, f[1].z); r[7] = __fmul_rn(f[1].w, f[1].w);
    #pragma unroll
    for (int i = 1; i < 8; ++i) {
        const float4 a = f[2 * i], c = f[2 * i + 1];
        r[0] = __fadd_rn(r[0], __fmul_rn(a.x, a.x));
        r[1] = __fadd_rn(r[1], __fmul_rn(a.y, a.y));
        r[2] = __fadd_rn(r[2], __fmul_rn(a.z, a.z));
        r[3] = __fadd_rn(r[3], __fmul_rn(a.w, a.w));
        r[4] = __fadd_rn(r[4], __fmul_rn(c.x, c.x));
        r[5] = __fadd_rn(r[5], __fmul_rn(c.y, c.y));
        r[6] = __fadd_rn(r[6], __fmul_rn(c.z, c.z));
        r[7] = __fadd_rn(r[7], __fmul_rn(c.w, c.w));
    }
    e_sq[k] = __fadd_rn(
        __fadd_rn(__fadd_rn(r[0], r[1]), __fadd_rn(r[2], r[3])),
        __fadd_rn(__fadd_rn(r[4], r[5]), __fadd_rn(r[6], r[7])));

    unsigned buf[32];
    #pragma unroll
    for (int i = 0; i < 16; ++i) {
        buf[2 * i]     = f2bf(f[i].x) | (f2bf(f[i].y) << 16);
        buf[2 * i + 1] = f2bf(f[i].z) | (f2bf(f[i].w) << 16);
    }
    uint4* dst = (uint4*)(ebf + k * 32);
    #pragma unroll
    for (int i = 0; i < 8; ++i) dst[i] = ((const uint4*)buf)[i];
}

__global__ __launch_bounds__(512, 4) void vq_main(const float* __restrict__ x,
                                                  const float* __restrict__ emb,
                                                  const float* __restrict__ e_sq,
                                                  const unsigned* __restrict__ ebf,
                                                  float* __restrict__ out)
{
    __shared__ float    xt[MPB][68];         // 17408 B exact x
    __shared__ _Float16 xbf[MPB][72];        //  9216 B bf16 x (A-frags)
    __shared__ float    axp[MPB][10];        //  2560 B |x| partials (pad->2-way)
    __shared__ unsigned pthr[MPB];           //   256 B ordered(min+margin)
    __shared__ unsigned long long bestpk[MPB]; // 512 B

    const int t    = threadIdx.x;
    const int pix0 = blockIdx.x * MPB;
    const int b    = pix0 >> 12;
    const int hw0  = pix0 & 4095;
    const float* xb = x + ((size_t)b << 18) + hw0;

    const int l    = t & 63;
    const int w    = __builtin_amdgcn_readfirstlane(t >> 6);  // uniform wave id
    const int i15  = l & 15, quad = l >> 4;
    const int nbase = w * 64;

    // ---- issue x staging loads first (HBM/L3, longest latency) ----
    const float* xp = xb + ((size_t)(8 * w) << 12) + l;
    float v[8];
    #pragma unroll
    for (int j = 0; j < 8; ++j) v[j] = xp[(size_t)j << 12];

    // ---- prefetch B-frags + e_sq (L2) before the barrier ----
    bf16x8 bfr[4][2];
    #pragma unroll
    for (int nt = 0; nt < 4; ++nt)
        #pragma unroll
        for (int kc = 0; kc < 2; ++kc)
            bfr[nt][kc] = *(const bf16x8*)((const char*)ebf
                + (size_t)(nbase + nt * 16 + i15) * 128 + kc * 64 + quad * 16);
    float eqv[4];
    #pragma unroll
    for (int nt = 0; nt < 4; ++nt) eqv[nt] = e_sq[nbase + nt * 16 + i15];

    if (t < MPB) { pthr[t] = 0xFFFFFFFFu; bestpk[t] = ~0ull; }

    // ---- finish staging: f32 + bf16 + |x| partial ----
    {
        *(float4*)&xt[l][8 * w]     = make_float4(v[0], v[1], v[2], v[3]);
        *(float4*)&xt[l][8 * w + 4] = make_float4(v[4], v[5], v[6], v[7]);
        uint4 dp;
        dp.x = f2bf(v[0]) | (f2bf(v[1]) << 16);
        dp.y = f2bf(v[2]) | (f2bf(v[3]) << 16);
        dp.z = f2bf(v[4]) | (f2bf(v[5]) << 16);
        dp.w = f2bf(v[6]) | (f2bf(v[7]) << 16);
        *(uint4*)&xbf[l][8 * w] = dp;
        axp[l][w] = ((fabsf(v[0]) + fabsf(v[1])) + (fabsf(v[2]) + fabsf(v[3])))
                  + ((fabsf(v[4]) + fabsf(v[5])) + (fabsf(v[6]) + fabsf(v[7])));
    }
    __syncthreads();

    // ---- per-lane margin for pixel row l ----
    float marg;
    {
        const float2 g0 = *(const float2*)&axp[l][0];
        const float2 g1 = *(const float2*)&axp[l][2];
        const float2 g2 = *(const float2*)&axp[l][4];
        const float2 g3 = *(const float2*)&axp[l][6];
        const float ax = ((g0.x + g0.y) + (g1.x + g1.y))
                       + ((g2.x + g2.y) + (g3.x + g3.y));
        marg = fmaf(4.0e-5f, ax, 5.0e-4f);
    }

    // ---- MFMA screen, scores stay in VGPRs ----
    float s[4][4][4];                        // [mt][nt][r]
    #pragma unroll
    for (int mt = 0; mt < 4; ++mt) {
        const bf16x8 af0 = *(const bf16x8*)&xbf[mt * 16 + i15][quad * 8];
        const bf16x8 af1 = *(const bf16x8*)&xbf[mt * 16 + i15][quad * 8 + 32];
        #pragma unroll
        for (int nt = 0; nt < 4; ++nt) {
            f32x4 acc = {0.f, 0.f, 0.f, 0.f};
            acc = __builtin_amdgcn_mfma_f32_16x16x32_bf16(af0, bfr[nt][0], acc, 0, 0, 0);
            acc = __builtin_amdgcn_mfma_f32_16x16x32_bf16(af1, bfr[nt][1], acc, 0, 0, 0);
            #pragma unroll
            for (int r = 0; r < 4; ++r)      // row=quad*4+r, col=i15
                s[mt][nt][r] = fmaf(-2.0f, acc[r], eqv[nt]);
        }
    }
    // per-row slice min: nt-fold, shfl-xor across 16 col lanes, +margin, atomicMin
    #pragma unroll
    for (int mt = 0; mt < 4; ++mt)
        #pragma unroll
        for (int r = 0; r < 4; ++r) {
            float vm = fminf(fminf(s[mt][0][r], s[mt][1][r]),
                             fminf(s[mt][2][r], s[mt][3][r]));
            vm = fminf(vm, __shfl_xor(vm, 1));
            vm = fminf(vm, __shfl_xor(vm, 2));
            vm = fminf(vm, __shfl_xor(vm, 4));
            vm = fminf(vm, __shfl_xor(vm, 8));
            const int row = mt * 16 + quad * 4 + r;
            const float mrow = __shfl(marg, row);
            if (i15 == 0) atomicMin(&pthr[row], ordf(__fadd_rn(vm, mrow)));
        }
    __syncthreads();

    // ---- candidate detect + inline exact np-semantics rescore ----
    {
        float tr[4][4];
        #pragma unroll
        for (int mt = 0; mt < 4; ++mt)
            #pragma unroll
            for (int r = 0; r < 4; ++r)
                tr[mt][r] = ordinv(pthr[mt * 16 + quad * 4 + r]);

        unsigned long long m = 0;
        #pragma unroll
        for (int mt = 0; mt < 4; ++mt)
            #pragma unroll
            for (int nt = 0; nt < 4; ++nt)
                #pragma unroll
                for (int r = 0; r < 4; ++r)
                    if (s[mt][nt][r] < tr[mt][r])            // rare
                        m |= 1ull << ((mt * 4 + nt) * 4 + r);

        while (m) {                                          // single rescore body
            const int bit = __builtin_ctzll(m);
            m &= m - 1;
            const int mt = bit >> 4, nt = (bit >> 2) & 3, r = bit & 3;
            const int p2 = mt * 16 + quad * 4 + r;
            const int k  = nbase + nt * 16 + i15;
            const float xs = xsq_pairwise8(xt[p2]);
            const float* er = emb + (size_t)k * CDIM;
            float d = 0.f;
            #pragma unroll
            for (int c4 = 0; c4 < 16; ++c4) {    // sequential-c fmaf = np order
                const float4 xv = *(const float4*)&xt[p2][4 * c4];
                const float4 ev = *(const float4*)&er[4 * c4];
                d = fmaf(xv.x, ev.x, d);
                d = fmaf(xv.y, ev.y, d);
                d = fmaf(xv.z, ev.z, d);
                d = fmaf(xv.w, ev.w, d);
            }
            const float se = __fsub_rn(__fadd_rn(xs, e_sq[k]),
                                       __fmul_rn(2.0f, d));
            const unsigned long long pkd =
                ((unsigned long long)ordf(se) << 32) | (unsigned)k;
            atomicMin(&bestpk[p2], pkd);         // lexicographic (se, k)
        }
    }
    __syncthreads();

    // ---- gather winning emb row (bit-exact) -> [B,C,H,W] ----
    {
        const int wi = (int)(bestpk[l] & 0xFFFFu);
        const float* ew = emb + (size_t)wi * CDIM + 8 * w;
        const float4 e0 = *(const float4*)ew;
        const float4 e1 = *(const float4*)(ew + 4);
        float* ob = out + ((size_t)b << 18) + (((size_t)(8 * w)) << 12) + hw0 + l;
        ob[(size_t)0 << 12] = e0.x;
        ob[(size_t)1 << 12] = e0.y;
        ob[(size_t)2 << 12] = e0.z;
        ob[(size_t)3 << 12] = e0.w;
        ob[(size_t)4 << 12] = e1.x;
        ob[(size_t)5 << 12] = e1.y;
        ob[(size_t)6 << 12] = e1.z;
        ob[(size_t)7 << 12] = e1.w;
    }
}

extern "C" void kernel_launch(void* const* d_in, const int* in_sizes, int n_in,
                              void* d_out, int out_size, void* d_ws, size_t ws_size,
                              hipStream_t stream)
{
    const float* x   = (const float*)d_in[0];
    const float* emb = (const float*)d_in[1];
    float* out  = (float*)d_out;
    float*    e_sq = (float*)d_ws;                 // 2 KB
    unsigned* ebf  = (unsigned*)d_ws + KNUM;       // 64 KB bf16 emb

    hipLaunchKernelGGL(vq_prep, dim3(KNUM / 64), dim3(64), 0, stream, emb, e_sq, ebf);
    const int nblocks = (32 * 64 * 64) / MPB;      // 2048
    hipLaunchKernelGGL(vq_main, dim3(nblocks), dim3(512), 0, stream,
                       x, emb, e_sq, ebf, out);
}

// Round 2
// 119.312 us; speedup vs baseline: 1.2085x; 1.0596x over previous
//
#include <hip/hip_runtime.h>

// VectorQuantizer: x [32,64,64,64] f32, emb [512,64] f32 -> out [32,64,64,64] f32
// R12: VALU diet via MFMA operand swap (A=codes, B=pixels -> D[code][pixel]).
//  - per-pixel min over codes: 15 in-lane fmin + 2 shfl (xor16/xor32) per nt,
//    vs R11's 4-shfl tree x 16 rows; threshold reads at detect 16 -> 4
//  - e_sq + (-2) folded into MFMA: prep stores bf16(-2e) (exact x2 scaling),
//    acc C-init = e_sq float4 -> deletes 64-fmaf epilogue (screen perturbation
//    ~1e-9 << 5e-4 margin floor; heuristic only, exact rescore decides)
//  - per-pixel xsq + margin precomputed to LDS by wave 0 between barriers
//    (read strictly after barrier 2 -> race-free); rescore drops xsq recompute
// Exact-score semantics unchanged from R8-R11 (absmax==0): sequential-c fmaf
// dot, pairwise-8 sums, _rn combine, lexicographic (se,k) u64 atomicMin.

#define KNUM 512
#define CDIM 64
#define MPB  64

typedef __attribute__((ext_vector_type(8))) short bf16x8;
typedef __attribute__((ext_vector_type(4))) float f32x4;

__device__ __forceinline__ unsigned f2bf(float f) {   // RNE f32->bf16
    unsigned u = __float_as_uint(f);
    return (u + 0x7FFFu + ((u >> 16) & 1u)) >> 16;
}
__device__ __forceinline__ unsigned ordf(float f) {   // total-order encode
    unsigned u = __float_as_uint(f);
    return u ^ ((unsigned)(((int)u) >> 31) | 0x80000000u);
}
__device__ __forceinline__ float ordinv(unsigned u) {
    unsigned fb = (u & 0x80000000u) ? (u ^ 0x80000000u) : ~u;
    return __uint_as_float(fb);
}

__device__ __forceinline__ float xsq_pairwise8(const float* xr)   // np order
{
    float r[8];
    {
        const float4 a = *(const float4*)&xr[0];
        const float4 c = *(const float4*)&xr[4];
        r[0] = __fmul_rn(a.x, a.x); r[1] = __fmul_rn(a.y, a.y);
        r[2] = __fmul_rn(a.z, a.z); r[3] = __fmul_rn(a.w, a.w);
        r[4] = __fmul_rn(c.x, c.x); r[5] = __fmul_rn(c.y, c.y);
        r[6] = __fmul_rn(c.z, c.z); r[7] = __fmul_rn(c.w, c.w);
    }
    #pragma unroll
    for (int i = 1; i < 8; ++i) {
        const float4 a = *(const float4*)&xr[8 * i];
        const float4 c = *(const float4*)&xr[8 * i + 4];
        r[0] = __fadd_rn(r[0], __fmul_rn(a.x, a.x));
        r[1] = __fadd_rn(r[1], __fmul_rn(a.y, a.y));
        r[2] = __fadd_rn(r[2], __fmul_rn(a.z, a.z));
        r[3] = __fadd_rn(r[3], __fmul_rn(a.w, a.w));
        r[4] = __fadd_rn(r[4], __fmul_rn(c.x, c.x));
        r[5] = __fadd_rn(r[5], __fmul_rn(c.y, c.y));
        r[6] = __fadd_rn(r[6], __fmul_rn(c.z, c.z));
        r[7] = __fadd_rn(r[7], __fmul_rn(c.w, c.w));
    }
    return __fadd_rn(
        __fadd_rn(__fadd_rn(r[0], r[1]), __fadd_rn(r[2], r[3])),
        __fadd_rn(__fadd_rn(r[4], r[5]), __fadd_rn(r[6], r[7])));
}

__global__ __launch_bounds__(64) void vq_prep(const float* __restrict__ emb,
                                              float* __restrict__ e_sq,
                                              unsigned* __restrict__ ebf)
{
    const int k = blockIdx.x * 64 + threadIdx.x;
    const float* e = emb + k * CDIM;
    float4 f[16];
    #pragma unroll
    for (int i = 0; i < 16; ++i) f[i] = ((const float4*)e)[i];

    float r[8];
    r[0] = __fmul_rn(f[0].x, f[0].x); r[1] = __fmul_rn(f[0].y, f[0].y);
    r[2] = __fmul_rn(f[0].z, f[0].z); r[3] = __fmul_rn(f[0].w, f[0].w);
    r[4] = __fmul_rn(f[1].x, f[1].x); r[5] = __fmul_rn(f[1].y, f[1].y);
    r[6] = __fmul_rn(f[1].z, f[1].z); r[7] = __fmul_rn(f[1].w, f[1].w);
    #pragma unroll
    for (int i = 1; i < 8; ++i) {
        const float4 a = f[2 * i], c = f[2 * i + 1];
        r[0] = __fadd_rn(r[0], __fmul_rn(a.x, a.x));
        r[1] = __fadd_rn(r[1], __fmul_rn(a.y, a.y));
        r[2] = __fadd_rn(r[2], __fmul_rn(a.z, a.z));
        r[3] = __fadd_rn(r[3], __fmul_rn(a.w, a.w));
        r[4] = __fadd_rn(r[4], __fmul_rn(c.x, c.x));
        r[5] = __fadd_rn(r[5], __fmul_rn(c.y, c.y));
        r[6] = __fadd_rn(r[6], __fmul_rn(c.z, c.z));
        r[7] = __fadd_rn(r[7], __fmul_rn(c.w, c.w));
    }
    e_sq[k] = __fadd_rn(
        __fadd_rn(__fadd_rn(r[0], r[1]), __fadd_rn(r[2], r[3])),
        __fadd_rn(__fadd_rn(r[4], r[5]), __fadd_rn(r[6], r[7])));

    // bf16(-2e): exact power-of-2 scale, products are exactly -2x original
    unsigned buf[32];
    #pragma unroll
    for (int i = 0; i < 16; ++i) {
        buf[2 * i]     = f2bf(__fmul_rn(-2.0f, f[i].x))
                       | (f2bf(__fmul_rn(-2.0f, f[i].y)) << 16);
        buf[2 * i + 1] = f2bf(__fmul_rn(-2.0f, f[i].z))
                       | (f2bf(__fmul_rn(-2.0f, f[i].w)) << 16);
    }
    uint4* dst = (uint4*)(ebf + k * 32);
    #pragma unroll
    for (int i = 0; i < 8; ++i) dst[i] = ((const uint4*)buf)[i];
}

__global__ __launch_bounds__(512, 4) void vq_main(const float* __restrict__ x,
                                                  const float* __restrict__ emb,
                                                  const float* __restrict__ e_sq,
                                                  const unsigned* __restrict__ ebf,
                                                  float* __restrict__ out)
{
    __shared__ float    xt[MPB][68];           // 17408 B exact x
    __shared__ _Float16 xbf[MPB][72];          //  9216 B bf16 x (B-frags)
    __shared__ float    axp[MPB][10];          //  2560 B |x| partials
    __shared__ float    margl[MPB];            //   256 B per-pixel margin
    __shared__ float    xsql[MPB];             //   256 B per-pixel ||x||^2
    __shared__ unsigned pthr[MPB];             //   256 B ordered screen min
    __shared__ unsigned long long bestpk[MPB]; //   512 B

    const int t    = threadIdx.x;
    const int pix0 = blockIdx.x * MPB;
    const int b    = pix0 >> 12;
    const int hw0  = pix0 & 4095;
    const float* xb = x + ((size_t)b << 18) + hw0;

    const int l    = t & 63;
    const int w    = __builtin_amdgcn_readfirstlane(t >> 6);  // uniform wave id
    const int i15  = l & 15, quad = l >> 4;
    const int nbase = w * 64;

    // ---- issue x staging loads first (HBM/L3, longest latency) ----
    const float* xp = xb + ((size_t)(8 * w) << 12) + l;
    float v[8];
    #pragma unroll
    for (int j = 0; j < 8; ++j) v[j] = xp[(size_t)j << 12];

    // ---- prefetch code A-frags (bf16(-2e)) + e_sq C-inits (L2) ----
    bf16x8 efr[4][2];
    #pragma unroll
    for (int mt = 0; mt < 4; ++mt)
        #pragma unroll
        for (int kc = 0; kc < 2; ++kc)
            efr[mt][kc] = *(const bf16x8*)((const char*)ebf
                + (size_t)(nbase + mt * 16 + i15) * 128 + kc * 64 + quad * 16);
    f32x4 esql[4];
    #pragma unroll
    for (int mt = 0; mt < 4; ++mt)
        esql[mt] = *(const f32x4*)(e_sq + nbase + mt * 16 + quad * 4);

    if (t < MPB) { pthr[t] = 0xFFFFFFFFu; bestpk[t] = ~0ull; }

    // ---- finish staging: f32 + bf16 + |x| partial ----
    {
        *(float4*)&xt[l][8 * w]     = make_float4(v[0], v[1], v[2], v[3]);
        *(float4*)&xt[l][8 * w + 4] = make_float4(v[4], v[5], v[6], v[7]);
        uint4 dp;
        dp.x = f2bf(v[0]) | (f2bf(v[1]) << 16);
        dp.y = f2bf(v[2]) | (f2bf(v[3]) << 16);
        dp.z = f2bf(v[4]) | (f2bf(v[5]) << 16);
        dp.w = f2bf(v[6]) | (f2bf(v[7]) << 16);
        *(uint4*)&xbf[l][8 * w] = dp;
        axp[l][w] = ((fabsf(v[0]) + fabsf(v[1])) + (fabsf(v[2]) + fabsf(v[3])))
                  + ((fabsf(v[4]) + fabsf(v[5])) + (fabsf(v[6]) + fabsf(v[7])));
    }
    __syncthreads();

    // ---- wave 0: per-pixel margin + exact ||x||^2 (read after barrier 2) ----
    if (t < MPB) {
        const float ax = ((axp[t][0] + axp[t][1]) + (axp[t][2] + axp[t][3]))
                       + ((axp[t][4] + axp[t][5]) + (axp[t][6] + axp[t][7]));
        margl[t] = fmaf(4.0e-5f, ax, 5.0e-4f);
        xsql[t]  = xsq_pairwise8(xt[t]);
    }

    // ---- MFMA screen: D[code][pixel] = e_sq[code] + (-2e).x ----
    float s[4][4][4];                          // [mt][nt][r], code-major
    #pragma unroll
    for (int nt = 0; nt < 4; ++nt) {
        const bf16x8 xf0 = *(const bf16x8*)&xbf[nt * 16 + i15][quad * 8];
        const bf16x8 xf1 = *(const bf16x8*)&xbf[nt * 16 + i15][quad * 8 + 32];
        #pragma unroll
        for (int mt = 0; mt < 4; ++mt) {
            f32x4 acc = esql[mt];              // C-init = e_sq[code row]
            acc = __builtin_amdgcn_mfma_f32_16x16x32_bf16(efr[mt][0], xf0, acc, 0, 0, 0);
            acc = __builtin_amdgcn_mfma_f32_16x16x32_bf16(efr[mt][1], xf1, acc, 0, 0, 0);
            #pragma unroll
            for (int r = 0; r < 4; ++r)        // code=quad*4+r(+16mt), pixel=i15(+16nt)
                s[mt][nt][r] = acc[r];
        }
    }
    // per-pixel min over this wave's 64 codes: 15 in-lane fmin + 2 shfl
    #pragma unroll
    for (int nt = 0; nt < 4; ++nt) {
        float mm[4];
        #pragma unroll
        for (int mt = 0; mt < 4; ++mt)
            mm[mt] = fminf(fminf(s[mt][nt][0], s[mt][nt][1]),
                           fminf(s[mt][nt][2], s[mt][nt][3]));
        float mv = fminf(fminf(mm[0], mm[1]), fminf(mm[2], mm[3]));
        mv = fminf(mv, __shfl_xor(mv, 16));
        mv = fminf(mv, __shfl_xor(mv, 32));
        if (quad == 0) atomicMin(&pthr[nt * 16 + i15], ordf(mv));
    }
    __syncthreads();

    // ---- candidate detect + inline exact np-semantics rescore ----
    {
        float tr[4];
        #pragma unroll
        for (int nt = 0; nt < 4; ++nt)
            tr[nt] = __fadd_rn(ordinv(pthr[nt * 16 + i15]),
                               margl[nt * 16 + i15]);

        unsigned long long m = 0;
        #pragma unroll
        for (int mt = 0; mt < 4; ++mt)
            #pragma unroll
            for (int nt = 0; nt < 4; ++nt)
                #pragma unroll
                for (int r = 0; r < 4; ++r)
                    if (s[mt][nt][r] < tr[nt])               // rare
                        m |= 1ull << (mt * 16 + nt * 4 + r);

        while (m) {                                          // single rescore body
            const int bit = __builtin_ctzll(m);
            m &= m - 1;
            const int mt = bit >> 4, nt = (bit >> 2) & 3, r = bit & 3;
            const int p2 = nt * 16 + i15;                    // pixel
            const int k  = nbase + mt * 16 + quad * 4 + r;   // code
            const float xs = xsql[p2];
            const float* er = emb + (size_t)k * CDIM;
            float d = 0.f;
            #pragma unroll
            for (int c4 = 0; c4 < 16; ++c4) {    // sequential-c fmaf = np order
                const float4 xv = *(const float4*)&xt[p2][4 * c4];
                const float4 ev = *(const float4*)&er[4 * c4];
                d = fmaf(xv.x, ev.x, d);
                d = fmaf(xv.y, ev.y, d);
                d = fmaf(xv.z, ev.z, d);
                d = fmaf(xv.w, ev.w, d);
            }
            const float se = __fsub_rn(__fadd_rn(xs, e_sq[k]),
                                       __fmul_rn(2.0f, d));
            const unsigned long long pkd =
                ((unsigned long long)ordf(se) << 32) | (unsigned)k;
            atomicMin(&bestpk[p2], pkd);         // lexicographic (se, k)
        }
    }
    __syncthreads();

    // ---- gather winning emb row (bit-exact) -> [B,C,H,W] ----
    {
        const int wi = (int)(bestpk[l] & 0xFFFFu);
        const float* ew = emb + (size_t)wi * CDIM + 8 * w;
        const float4 e0 = *(const float4*)ew;
        const float4 e1 = *(const float4*)(ew + 4);
        float* ob = out + ((size_t)b << 18) + (((size_t)(8 * w)) << 12) + hw0 + l;
        ob[(size_t)0 << 12] = e0.x;
        ob[(size_t)1 << 12] = e0.y;
        ob[(size_t)2 << 12] = e0.z;
        ob[(size_t)3 << 12] = e0.w;
        ob[(size_t)4 << 12] = e1.x;
        ob[(size_t)5 << 12] = e1.y;
        ob[(size_t)6 << 12] = e1.z;
        ob[(size_t)7 << 12] = e1.w;
    }
}

extern "C" void kernel_launch(void* const* d_in, const int* in_sizes, int n_in,
                              void* d_out, int out_size, void* d_ws, size_t ws_size,
                              hipStream_t stream)
{
    const float* x   = (const float*)d_in[0];
    const float* emb = (const float*)d_in[1];
    float* out  = (float*)d_out;
    float*    e_sq = (float*)d_ws;                 // 2 KB
    unsigned* ebf  = (unsigned*)d_ws + KNUM;       // 64 KB bf16(-2e)

    hipLaunchKernelGGL(vq_prep, dim3(KNUM / 64), dim3(64), 0, stream, emb, e_sq, ebf);
    const int nblocks = (32 * 64 * 64) / MPB;      // 2048
    hipLaunchKernelGGL(vq_main, dim3(nblocks), dim3(512), 0, stream,
                       x, emb, e_sq, ebf, out);
}